// Round 5
// baseline (1238.477 us; speedup 1.0000x reference)
//
#include <hip/hip_runtime.h>
#include <cstddef>

// ---------------------------------------------------------------------------
// WaveletNet on MI355X — round 5: templated-Cin MFMA convs, BK=64, constant
// pointer increments (no per-chunk branch), XCD-aware block swizzle.
// Zero-padded NHWC + global_load_lds width-16, 2-barrier K-loop.
// ---------------------------------------------------------------------------

typedef unsigned short u16;
typedef unsigned int u32;
typedef __bf16 bf16x8 __attribute__((ext_vector_type(8)));
typedef float floatx4 __attribute__((ext_vector_type(4)));
typedef u16 u16x4 __attribute__((ext_vector_type(4)));
typedef u16 u16x8 __attribute__((ext_vector_type(8)));

__device__ __forceinline__ float b2f(u16 h) {
    union { u32 u; float f; } x; x.u = ((u32)h) << 16; return x.f;
}
__device__ __forceinline__ u16 f2b(float f) {
    union { float f; u32 u; } x; x.f = f;
    return (u16)((x.u + 0x7FFFu + ((x.u >> 16) & 1u)) >> 16);
}
__device__ __forceinline__ float lrelu_f(float v) { return v > 0.f ? v : 0.2f * v; }

// async global->LDS, 16B per lane; LDS dest = wave-uniform base + lane*16
__device__ __forceinline__ void gld16(const u16* g, u16* l) {
    __builtin_amdgcn_global_load_lds(
        (const __attribute__((address_space(1))) u32*)(const void*)g,
        (__attribute__((address_space(3))) u32*)(void*)l, 16, 0, 0);
}

// ---------------- MFMA implicit-GEMM conv3x3, padded NHWC, BK=64 ----------------
// A[m][k], k = tap*CIN+ci; input padded [B][H+2][W+2][CIN], border zero.
// Wb=[Cout][9*CIN]. BM=128, BN=64, BK=64. 4 waves 2x2; per-wave 4x2 16x16 tiles.
// Grid = 1D, XCD-swizzled: xcd = bid&7 owns m-stripe [xcd*mPerX, ...) x all n.
template<int CIN, int LOGNN>
__global__ __launch_bounds__(256)
void conv_mfma_k(const u16* __restrict__ in, int iWp, int iImg,
                 const u16* __restrict__ wb, const float* __restrict__ bias,
                 const u16* __restrict__ skip, int sC, int sWp, int sImg, int spad,
                 u16* __restrict__ out, int Cst, int oWp, int oImg, int opad,
                 int logW, int logH)
{
    constexpr int K = 9 * CIN;
    __shared__ u16 At[128 * 64];   // 16 KB, row = 64 bf16 = 128 B
    __shared__ u16 Bt[64 * 64];    //  8 KB

    const int tid = threadIdx.x;
    const int wid = tid >> 6, lane = tid & 63;
    const int W = 1 << logW, H = 1 << logH;

    // XCD-aware swizzle: same-m blocks (all n) land on one XCD
    const int bid = blockIdx.x;
    const int xcd = bid & 7;
    const int l = bid >> 3;
    const int nIdx = l & ((1 << LOGNN) - 1);
    const int mloc = l >> LOGNN;
    const int mPerX = (int)gridDim.x >> (3 + LOGNN);
    const int mBase = (xcd * mPerX + mloc) * 128;
    const int nBase = nIdx * 64;

    const int lr = lane >> 3;          // row-within-8 group
    const int lc = (lane & 7) * 8;     // channel offset (8 ch = 16 B)

    // A: 4 gld16/wave/chunk, rows wid*32 + j*8 + lr
    const u16* gA[4];
#pragma unroll
    for (int j = 0; j < 4; ++j) {
        int m = mBase + wid * 32 + j * 8 + lr;
        int px = m & (W - 1), py = (m >> logW) & (H - 1), pb = m >> (logW + logH);
        gA[j] = in + ((size_t)pb * iImg + (size_t)py * iWp + px) * CIN + lc;
    }
    // B: 2 gld16/wave/chunk, rows wid*16 + j*8 + lr
    const u16* gB[2];
#pragma unroll
    for (int j = 0; j < 2; ++j)
        gB[j] = wb + (size_t)(nBase + wid * 16 + j * 8 + lr) * K + lc;

    u16* lA[4];
#pragma unroll
    for (int j = 0; j < 4; ++j) lA[j] = &At[wid * 2048 + j * 512];
    u16* lB[2];
#pragma unroll
    for (int j = 0; j < 2; ++j) lB[j] = &Bt[wid * 1024 + j * 512];

    const int wm = wid >> 1, wn = wid & 1;
    const int fm = lane & 15, fq = (lane >> 4) * 16;   // byte offset of k-group

    floatx4 acc[4][2] = {};

    const size_t tapAdj = (size_t)(iWp - 3) * CIN;     // after taps 2 and 5

    for (int tap = 0; tap < 9; ++tap) {
#pragma unroll 2
        for (int c = 0; c < CIN / 64; ++c) {
            gld16(gA[0], lA[0]); gld16(gA[1], lA[1]);
            gld16(gA[2], lA[2]); gld16(gA[3], lA[3]);
            gld16(gB[0], lB[0]); gld16(gB[1], lB[1]);
            __syncthreads();
#pragma unroll
            for (int kh = 0; kh < 2; ++kh) {
                bf16x8 af[4], bfr[2];
#pragma unroll
                for (int mt = 0; mt < 4; ++mt)
                    af[mt] = *(const bf16x8*)((const char*)At +
                              (wm * 64 + mt * 16 + fm) * 128 + kh * 64 + fq);
#pragma unroll
                for (int nt = 0; nt < 2; ++nt)
                    bfr[nt] = *(const bf16x8*)((const char*)Bt +
                               (wn * 32 + nt * 16 + fm) * 128 + kh * 64 + fq);
#pragma unroll
                for (int mt = 0; mt < 4; ++mt)
#pragma unroll
                    for (int nt = 0; nt < 2; ++nt)
                        acc[mt][nt] = __builtin_amdgcn_mfma_f32_16x16x32_bf16(
                            af[mt], bfr[nt], acc[mt][nt], 0, 0, 0);
            }
            __syncthreads();
            // compile-time constant advance: +64 channels (== next pixel at slice end)
#pragma unroll
            for (int j = 0; j < 4; ++j) gA[j] += 64;
            gB[0] += 64; gB[1] += 64;
        }
        if (tap == 2 || tap == 5) {
#pragma unroll
            for (int j = 0; j < 4; ++j) gA[j] += tapAdj;
        }
    }

    // epilogue: bias (+skip) + lrelu -> bf16 NHWC (padded or flat out)
    const int rq = (lane >> 4) * 4;
#pragma unroll
    for (int mt = 0; mt < 4; ++mt) {
        const int mrow = mBase + wm * 64 + mt * 16 + rq;
#pragma unroll
        for (int r = 0; r < 4; ++r) {
            int m2 = mrow + r;
            int px = m2 & (W - 1), py = (m2 >> logW) & (H - 1), pb = m2 >> (logW + logH);
            size_t ob = ((size_t)pb * oImg + (size_t)(py + opad) * oWp + (px + opad)) * Cst;
            size_t sb = 0;
            if (skip) sb = ((size_t)pb * sImg + (size_t)(py + spad) * sWp + (px + spad)) * sC;
#pragma unroll
            for (int nt = 0; nt < 2; ++nt) {
                int n = nBase + wn * 32 + nt * 16 + fm;
                float v = acc[mt][nt][r] + bias[n];
                if (skip) v += b2f(skip[sb + n]);
                v = lrelu_f(v);
                out[ob + n] = f2b(v);
            }
        }
    }
}

// ---------------- MFMA conv3x3, Cin=32 -> Cout=16 (convd2), padded in, flat out ----
__global__ __launch_bounds__(256)
void conv_n16_k(const u16* __restrict__ in, int iWp, int iImg,
                const u16* __restrict__ wb, const float* __restrict__ bias,
                u16* __restrict__ out, int logW, int logH)
{
    __shared__ u16 At[128 * 32];    // 8 KB
    __shared__ u16 Bt[16 * 32];     // 1 KB
    const int tid = threadIdx.x;
    const int wid = tid >> 6, lane = tid & 63;
    const int W = 1 << logW, H = 1 << logH;
    const int mBase = blockIdx.x * 128;
    const int kg = lane & 3, rr = lane >> 2;

    const u16 *gA0, *gA1;
    {
        int m0 = mBase + wid * 32 + rr;
        int px0 = m0 & (W - 1), py0 = (m0 >> logW) & (H - 1), pb0 = m0 >> (logW + logH);
        gA0 = in + ((size_t)pb0 * iImg + (size_t)py0 * iWp + px0) * 32 + kg * 8;
        int m1 = m0 + 16;
        int px1 = m1 & (W - 1), py1 = (m1 >> logW) & (H - 1), pb1 = m1 >> (logW + logH);
        gA1 = in + ((size_t)pb1 * iImg + (size_t)py1 * iWp + px1) * 32 + kg * 8;
    }
    const u16* gB = wb + (size_t)rr * 288 + kg * 8;   // 16 rows (rr<16 used)
    u16* lA0 = &At[wid * 1024];
    u16* lA1 = &At[wid * 1024 + 512];

    const int fm = lane & 15, fkh = (lane >> 4) * 8;
    floatx4 acc[2] = {};
    const size_t rowStep = (size_t)(iWp - 2) * 32;

    for (int tap = 0; tap < 9; ++tap) {
        gld16(gA0, lA0);
        gld16(gA1, lA1);
        if (wid == 0) gld16(gB, &Bt[0]);
        __syncthreads();
        bf16x8 bf = *(const bf16x8*)&Bt[fm * 32 + fkh];
#pragma unroll
        for (int mt = 0; mt < 2; ++mt) {
            bf16x8 af = *(const bf16x8*)&At[(wid * 32 + mt * 16 + fm) * 32 + fkh];
            acc[mt] = __builtin_amdgcn_mfma_f32_16x16x32_bf16(af, bf, acc[mt], 0, 0, 0);
        }
        __syncthreads();
        size_t dA = (tap % 3 == 2) ? rowStep : (size_t)32;
        gA0 += dA; gA1 += dA; gB += 32;
    }

    const int rq = (lane >> 4) * 4;
    const float bn = bias[fm];
#pragma unroll
    for (int mt = 0; mt < 2; ++mt) {
#pragma unroll
        for (int r = 0; r < 4; ++r) {
            int m2 = mBase + wid * 32 + mt * 16 + rq + r;
            out[(size_t)m2 * 16 + fm] = f2b(lrelu_f(acc[mt][r] + bn));
        }
    }
}

// ---------------- direct NHWC conv3x3 (small channels), fp32 weights ----------------
template<int CIN, int COUT>
__global__ __launch_bounds__(256)
void conv_direct_k(const u16* __restrict__ in, int Sin,
                   const float* __restrict__ w, const float* __restrict__ bias,
                   u16* __restrict__ out, int Sout, int oWp, int oImg, int opad,
                   int logW, int logH, int total)
{
    int m = blockIdx.x * 256 + threadIdx.x;
    if (m >= total) return;
    const int W = 1 << logW, H = 1 << logH;
    const int px = m & (W - 1);
    const int py = (m >> logW) & (H - 1);
    const int pb = m >> (logW + logH);
    float acc[COUT];
#pragma unroll
    for (int o = 0; o < COUT; ++o) acc[o] = bias[o];
    for (int tap = 0; tap < 9; ++tap) {
        int dy = tap / 3 - 1, dx = tap % 3 - 1;
        int iy = py + dy, ix = px + dx;
        if ((unsigned)iy >= (unsigned)H || (unsigned)ix >= (unsigned)W) continue;
        const u16* p = in + (size_t)((((pb << logH) + iy) << logW) + ix) * Sin;
        if constexpr (CIN == 4) {
            u16x4 v = *(const u16x4*)p;
#pragma unroll
            for (int ci = 0; ci < 4; ++ci) {
                float f = b2f(v[ci]);
#pragma unroll
                for (int o = 0; o < COUT; ++o) acc[o] += f * w[(o * CIN + ci) * 9 + tap];
            }
        } else {
#pragma unroll
            for (int c8 = 0; c8 < CIN / 8; ++c8) {
                u16x8 v = *(const u16x8*)(p + c8 * 8);
#pragma unroll
                for (int j = 0; j < 8; ++j) {
                    int ci = c8 * 8 + j;
                    float f = b2f(v[j]);
#pragma unroll
                    for (int o = 0; o < COUT; ++o) acc[o] += f * w[(o * CIN + ci) * 9 + tap];
                }
            }
        }
    }
    size_t ob = ((size_t)pb * oImg + (size_t)(py + opad) * oWp + (px + opad)) * Sout;
#pragma unroll
    for (int o = 0; o < COUT; ++o)
        out[ob + o] = f2b(lrelu_f(acc[o]));
}

// ---------------- Haar wt / iwt, geometry-parametrized NHWC ----------------
__global__ __launch_bounds__(256)
void wt_in_k(const float* __restrict__ x, u16* __restrict__ out, int total)
{
    int idx = blockIdx.x * 256 + threadIdx.x;   // (b,h,w) of 8x256x256
    if (idx >= total) return;
    int wq = idx & 255, t = idx >> 8;
    int hq = t & 255, b = t >> 8;
    const float* p = x + ((size_t)b * 512 + 2 * hq) * 512 + 2 * wq;
    float a = p[0], bv = p[1], cv = p[512], d = p[513];
    u16x4 o = { f2b(0.25f * (a + bv + cv + d)),
                f2b(0.25f * (a + bv - cv - d) + 0.5f),
                f2b(0.25f * (a - bv + cv - d) + 0.5f),
                f2b(0.25f * (a - bv - cv + d) + 0.5f) };
    *(u16x4*)&out[(size_t)idx * 4] = o;
}

// in: maybe-padded NHWC [Sin]; out: maybe-padded NHWC [Sout], channels 4c+band
__global__ __launch_bounds__(256)
void wt_k(const u16* __restrict__ in, int Sin, int iWp, int iImg, int ipad,
          u16* __restrict__ out, int Sout, int oWp, int oImg, int opad,
          int logC, int logWo, int logHo, int total)
{
    int idx = blockIdx.x * 256 + threadIdx.x;
    if (idx >= total) return;
    const int C = 1 << logC, Wo = 1 << logWo, Ho = 1 << logHo;
    int c = idx & (C - 1); int t = idx >> logC;
    int wq = t & (Wo - 1); t >>= logWo;
    int hq = t & (Ho - 1); int b = t >> logHo;
    size_t p00 = ((size_t)b * iImg + (size_t)(2 * hq + ipad) * iWp + (2 * wq + ipad)) * Sin + c;
    float a  = b2f(in[p00]);
    float bv = b2f(in[p00 + Sin]);
    float cv = b2f(in[p00 + (size_t)iWp * Sin]);
    float d  = b2f(in[p00 + (size_t)iWp * Sin + Sin]);
    u16x4 o = { f2b(0.25f * (a + bv + cv + d)),
                f2b(0.25f * (a + bv - cv - d) + 0.5f),
                f2b(0.25f * (a - bv + cv - d) + 0.5f),
                f2b(0.25f * (a - bv - cv + d) + 0.5f) };
    *(u16x4*)&out[((size_t)b * oImg + (size_t)(hq + opad) * oWp + (wq + opad)) * Sout + 4 * c] = o;
}

// in: flat NHWC (unpadded), channels 4c+band; out: maybe-padded NHWC
__global__ __launch_bounds__(256)
void iwt_k(const u16* __restrict__ in, int Sin, int logC, int logW, int logH,
           u16* __restrict__ out, int Sout, int oWp, int oImg, int opad, int total)
{
    int idx = blockIdx.x * 256 + threadIdx.x;
    if (idx >= total) return;
    const int C = 1 << logC, W = 1 << logW;
    int c = idx & (C - 1); int t = idx >> logC;
    int wq = t & (W - 1); t >>= logW;
    int hq = t & ((1 << logH) - 1); int b = t >> logH;
    u16x4 v = *(const u16x4*)&in[(size_t)((((b << logH) + hq) << logW) + wq) * Sin + 4 * c];
    float y0 = b2f(v[0]);
    float y1 = 2.f * b2f(v[1]) - 1.f;
    float y2 = 2.f * b2f(v[2]) - 1.f;
    float y3 = 2.f * b2f(v[3]) - 1.f;
    float x00 = y0 + 0.5f * ( y1 + y2 + y3);
    float x01 = y0 + 0.5f * ( y1 - y2 - y3);
    float x10 = y0 + 0.5f * (-y1 + y2 - y3);
    float x11 = y0 + 0.5f * (-y1 - y2 + y3);
    size_t q = ((size_t)b * oImg + (size_t)(2 * hq + opad) * oWp + (2 * wq + opad)) * Sout + c;
    out[q] = f2b(x00);
    out[q + Sout] = f2b(x01);
    out[q + (size_t)oWp * Sout] = f2b(x10);
    out[q + (size_t)oWp * Sout + Sout] = f2b(x11);
}

__global__ __launch_bounds__(256)
void iwt_out_k(const u16* __restrict__ in, float* __restrict__ out, int total)
{
    int idx = blockIdx.x * 256 + threadIdx.x;   // (b,h,w) of 8x256x256
    if (idx >= total) return;
    int wq = idx & 255, t = idx >> 8;
    int hq = t & 255, b = t >> 8;
    u16x4 v = *(const u16x4*)&in[(size_t)idx * 4];
    float y0 = b2f(v[0]);
    float y1 = 2.f * b2f(v[1]) - 1.f;
    float y2 = 2.f * b2f(v[2]) - 1.f;
    float y3 = 2.f * b2f(v[3]) - 1.f;
    float x00 = y0 + 0.5f * ( y1 + y2 + y3);
    float x01 = y0 + 0.5f * ( y1 - y2 - y3);
    float x10 = y0 + 0.5f * (-y1 + y2 - y3);
    float x11 = y0 + 0.5f * (-y1 - y2 + y3);
    float* q = out + ((size_t)b * 512 + 2 * hq) * 512 + 2 * wq;
    q[0]   = 1.f / (1.f + __expf(-x00));
    q[1]   = 1.f / (1.f + __expf(-x01));
    q[512] = 1.f / (1.f + __expf(-x10));
    q[513] = 1.f / (1.f + __expf(-x11));
}

// ---------------- weight prep: [O][I][3][3] fp32 -> [O][tap][I] bf16 ----------------
__global__ __launch_bounds__(256)
void prep_w_k(const float* __restrict__ src, u16* __restrict__ dst, int logCIN, int total)
{
    int idx = blockIdx.x * 256 + threadIdx.x;
    if (idx >= total) return;
    const int CIN = 1 << logCIN;
    int ci = idx & (CIN - 1);
    int q = idx >> logCIN;
    int tap = q % 9, o = q / 9;
    dst[idx] = f2b(src[((size_t)(o * CIN + ci)) * 9 + tap]);
}

// ---------------- zero the 1-pixel border of a padded NHWC buffer ----------------
__global__ __launch_bounds__(256)
void zb_k(u16* __restrict__ buf, int Wp, int Hp, int C, int total)
{
    int idx = blockIdx.x * 256 + threadIdx.x;
    if (idx >= total) return;
    int c8 = idx % (C / 8); int t = idx / (C / 8);
    int nbp = 2 * Wp + 2 * (Hp - 2);
    int p = t % nbp; int b = t / nbp;
    int y, x;
    if (p < Wp) { y = 0; x = p; }
    else if (p < 2 * Wp) { y = Hp - 1; x = p - Wp; }
    else { int q = p - 2 * Wp; y = 1 + (q >> 1); x = (q & 1) ? Wp - 1 : 0; }
    u16x8 z = {0, 0, 0, 0, 0, 0, 0, 0};
    *(u16x8*)&buf[((size_t)b * Hp * Wp + (size_t)y * Wp + x) * C + c8 * 8] = z;
}

// ---------------------------------------------------------------------------
extern "C" void kernel_launch(void* const* d_in, const int* in_sizes, int n_in,
                              void* d_out, int out_size, void* d_ws, size_t ws_size,
                              hipStream_t stream)
{
    const float* x   = (const float*)d_in[0];
    const float* c1w = (const float*)d_in[1];  const float* c1b = (const float*)d_in[2];
    const float* c2w = (const float*)d_in[3];  const float* c2b = (const float*)d_in[4];
    const float* c3w = (const float*)d_in[5];  const float* c3b = (const float*)d_in[6];
    const float* c4w = (const float*)d_in[7];  const float* c4b = (const float*)d_in[8];
    const float* d1w = (const float*)d_in[9];  const float* d1b = (const float*)d_in[10];
    const float* d2w = (const float*)d_in[11]; const float* d2b = (const float*)d_in[12];
    const float* d3w = (const float*)d_in[13]; const float* d3b = (const float*)d_in[14];
    const float* d4w = (const float*)d_in[15]; const float* d4b = (const float*)d_in[16];

    const size_t MiB = 1u << 20;
    char* base = (char*)d_ws;
    // weights [0, 22 MiB)
    u16* c4wb = (u16*)base;                  // 9,437,184
    u16* c3wb = c4wb + 9437184;              //   589,824
    u16* d4wb = c3wb + 589824;               // 1,179,648
    u16* d3wb = d4wb + 1179648;              //    73,728
    u16* c2wb = d3wb + 73728;                //    36,864
    u16* d2wb = c2wb + 36864;                //     4,608
    // activations
    u16* CAT1p = (u16*)(base + 22  * MiB);   // [8,258,258,32]  padded: c1 | u2
    u16* CAT2p = (u16*)(base + 55  * MiB);   // [8,130,130,128] padded: c2 | u3
    u16* CAT3p = (u16*)(base + 88  * MiB);   // [8,66,66,512]   padded: c3 | u4
    u16* P1    = (u16*)(base + 123 * MiB);   // W2p -> W4p -> IC2
    u16* P2    = (u16*)(base + 142 * MiB);   // W3p -> C4p -> IC4 -> IC1
    u16* P3    = (u16*)(base + 161 * MiB);   // W1 -> C5p -> IC3 -> IW1
    float* outp = (float*)d_out;

    u16* W2p = P1; u16* W4p = P1; u16* IC2 = P1;
    u16* W3p = P2; u16* C4p = P2; u16* IC4 = P2; u16* IC1 = P2;
    u16* W1  = P3; u16* C5p = P3; u16* IC3 = P3; u16* IW1 = P3;

    auto cdiv = [](int a, int b) { return (a + b - 1) / b; };
    auto prep = [&](const float* s, u16* d, int logCIN, int total) {
        prep_w_k<<<cdiv(total, 256), 256, 0, stream>>>(s, d, logCIN, total);
    };
    auto zb = [&](u16* buf, int Wp, int Hp, int C) {
        int total = 8 * (2 * Wp + 2 * (Hp - 2)) * (C / 8);
        zb_k<<<cdiv(total, 256), 256, 0, stream>>>(buf, Wp, Hp, C, total);
    };

    // weight prep
    prep(c4w, c4wb, 10, 9437184);
    prep(c3w, c3wb, 8, 589824);
    prep(d4w, d4wb, 9, 1179648);
    prep(d3w, d3wb, 7, 73728);
    prep(c2w, c2wb, 6, 36864);
    prep(d2w, d2wb, 5, 4608);
    // borders whose slots have no earlier tenant
    zb(CAT1p, 258, 258, 32);
    zb(W2p, 130, 130, 64);
    zb(W3p, 66, 66, 256);
    zb(CAT2p, 130, 130, 128);
    zb(CAT3p, 66, 66, 512);

    const int P256 = 8 * 256 * 256;
    const int T2M = 2097152;      // 8*128*128*16 == 8*64*64*64 == 8*32*32*256
    const int I258 = 258 * 258;   // padded 256-image plane

    // w1 = wt(x) -> W1 (flat [8,256,256,4])
    wt_in_k<<<cdiv(P256, 256), 256, 0, stream>>>(x, W1, P256);
    // c1 -> CAT1p interior ch0..15 (direct, fp32 weights)
    conv_direct_k<4, 16><<<cdiv(P256, 256), 256, 0, stream>>>(
        W1, 4, c1w, c1b, CAT1p, 32, 258, I258, 1, 8, 8, P256);
    zb(C5p, 34, 34, 1024);                      // P3 free of W1 now
    // w2 = wt(c1) -> W2p padded [8,130,130,64]
    wt_k<<<cdiv(T2M, 256), 256, 0, stream>>>(CAT1p, 32, 258, I258, 1,
                                             W2p, 64, 130, 16900, 1, 4, 7, 7, T2M);
    // c2 = lrelu(conv2(w2)) -> CAT2p interior ch0..63   (M=131072: 1024 m-blocks, NN=1)
    conv_mfma_k<64, 0><<<dim3(1024), 256, 0, stream>>>(
        W2p, 130, 16900, c2wb, c2b, nullptr, 0, 0, 0, 0,
        CAT2p, 128, 130, 16900, 1, 7, 7);
    zb(W4p, 34, 34, 1024);                      // P1 free of W2p now
    // w3 = wt(c2) -> W3p padded [8,66,66,256]
    wt_k<<<cdiv(T2M, 256), 256, 0, stream>>>(CAT2p, 128, 130, 16900, 1,
                                             W3p, 256, 66, 4356, 1, 6, 6, 6, T2M);
    // c3 -> CAT3p interior ch0..255   (256 m-blocks x 4 n)
    conv_mfma_k<256, 2><<<dim3(1024), 256, 0, stream>>>(
        W3p, 66, 4356, c3wb, c3b, nullptr, 0, 0, 0, 0,
        CAT3p, 512, 66, 4356, 1, 6, 6);
    zb(C4p, 34, 34, 1024);                      // P2 free of W3p now
    // w4 = wt(c3) -> W4p padded [8,34,34,1024]
    wt_k<<<cdiv(T2M, 256), 256, 0, stream>>>(CAT3p, 512, 66, 4356, 1,
                                             W4p, 1024, 34, 1156, 1, 8, 5, 5, T2M);
    // c4 -> C4p padded   (64 m-blocks x 16 n)
    conv_mfma_k<1024, 4><<<dim3(1024), 256, 0, stream>>>(
        W4p, 34, 1156, c4wb, c4b, nullptr, 0, 0, 0, 0,
        C4p, 1024, 34, 1156, 1, 5, 5);
    // c5 -> C5p padded
    conv_mfma_k<1024, 4><<<dim3(1024), 256, 0, stream>>>(
        C4p, 34, 1156, c4wb, c4b, nullptr, 0, 0, 0, 0,
        C5p, 1024, 34, 1156, 1, 5, 5);
    // ic4 = lrelu(conv4(c5) + w4) -> IC4 flat [8,32,32,1024]
    conv_mfma_k<1024, 4><<<dim3(1024), 256, 0, stream>>>(
        C5p, 34, 1156, c4wb, c4b, W4p, 1024, 34, 1156, 1,
        IC4, 1024, 32, 1024, 0, 5, 5);
    // u4 = iwt(ic4) -> CAT3p interior ch256..511
    iwt_k<<<cdiv(T2M, 256), 256, 0, stream>>>(IC4, 1024, 8, 5, 5,
                                              CAT3p + 256, 512, 66, 4356, 1, T2M);
    // ic3 = lrelu(convd4(cat3)) -> IC3 flat [8,64,64,256]   (256 m x 4 n)
    conv_mfma_k<512, 2><<<dim3(1024), 256, 0, stream>>>(
        CAT3p, 66, 4356, d4wb, d4b, nullptr, 0, 0, 0, 0,
        IC3, 256, 64, 4096, 0, 6, 6);
    // u3 = iwt(ic3) -> CAT2p interior ch64..127
    iwt_k<<<cdiv(T2M, 256), 256, 0, stream>>>(IC3, 256, 6, 6, 6,
                                              CAT2p + 64, 128, 130, 16900, 1, T2M);
    // ic2 = lrelu(convd3(cat2)) -> IC2 flat [8,128,128,64]   (1024 m x 1 n)
    conv_mfma_k<128, 0><<<dim3(1024), 256, 0, stream>>>(
        CAT2p, 130, 16900, d3wb, d3b, nullptr, 0, 0, 0, 0,
        IC2, 64, 128, 16384, 0, 7, 7);
    // u2 = iwt(ic2) -> CAT1p interior ch16..31
    iwt_k<<<cdiv(T2M, 256), 256, 0, stream>>>(IC2, 64, 4, 7, 7,
                                              CAT1p + 16, 32, 258, I258, 1, T2M);
    // ic1 = lrelu(convd2(cat1)) -> IC1 flat [8,256,256,16]  (MFMA, N=16)
    conv_n16_k<<<dim3(P256 / 128), 256, 0, stream>>>(CAT1p, 258, I258, d2wb, d2b, IC1, 8, 8);
    // iw1 = lrelu(convd1(ic1)) -> IW1 flat [8,256,256,4]
    conv_direct_k<16, 4><<<cdiv(P256, 256), 256, 0, stream>>>(
        IC1, 16, d1w, d1b, IW1, 4, 256, 65536, 0, 8, 8, P256);
    // out = sigmoid(iwt(iw1))
    iwt_out_k<<<cdiv(P256, 256), 256, 0, stream>>>(IW1, outp, P256);
}